// Round 4
// baseline (132.911 us; speedup 1.0000x reference)
//
#include <hip/hip_runtime.h>

#define NF 64

// workspace float offsets
#define OFF_NORMG   0          // 2048
#define OFF_NORMP   2048       // 2048
#define OFF_SG      4096       // 2048
#define OFF_SP      6144       // 2048
#define OFF_MAXG    8192       // 1 (float)
#define OFF_MAXP    8193       // 1 (float)
#define OFF_U       8194       // 128
#define OFF_HSUMG   8322       // 256
#define OFF_HSUMP   8578       // 256
#define OFF_C1      8834       // 4
#define OFF_NPG     9216       // 8*2048 partial row counts (g side)
#define OFF_NPP     25600      // 8*2048 partial col counts (p side)
#define OFF_HA_G    41984      // 131072
#define OFF_HA_P    173056
#define OFF_HB_G    304128
#define OFF_HB_P    435200
#define OFF_EG      566272
#define OFF_EP      697344
#define OFF_OBST    828416     // 1048576 floats

static __device__ __forceinline__ float wave_sum(float v) {
    for (int off = 32; off; off >>= 1) v += __shfl_down(v, off, 64);
    return v;
}
static __device__ __forceinline__ float wave_max(float v) {
    for (int off = 32; off; off >>= 1) v = fmaxf(v, __shfl_down(v, off, 64));
    return v;
}

// ---------------- K1: transpose obs -> obsT, partial row/col nonzero counts ----------------
__global__ __launch_bounds__(256) void k_prep(const float* __restrict__ obs,
                                              float* __restrict__ ws) {
    __shared__ float tile[64][65];
    __shared__ float cc[4][64];
    int b = blockIdx.y, t = threadIdx.x;
    int tg = blockIdx.x >> 3, tp = blockIdx.x & 7;
    int g0 = tg * 64, p0 = tp * 64;
    int c = t & 63, r0 = t >> 6;   // r0 = wave id (0..3)
    const float* src = obs + ((size_t)b * 512 + g0) * 512 + p0;
    float colcnt = 0.f;
#pragma unroll
    for (int i = 0; i < 16; ++i) {
        int r = r0 + 4 * i;
        float v = src[(size_t)r * 512 + c];
        tile[r][c] = v;
        float nz = (v != 0.f) ? 1.f : 0.f;
        colcnt += nz;
        nz = wave_sum(nz);
        if (c == 0) ws[OFF_NPG + tp * 2048 + b * 512 + g0 + r] = nz;
    }
    cc[r0][c] = colcnt;
    __syncthreads();
    if (r0 == 0)
        ws[OFF_NPP + tg * 2048 + b * 512 + p0 + c] =
            cc[0][c] + cc[1][c] + cc[2][c] + cc[3][c];
    float* dst = ws + OFF_OBST + ((size_t)b * 512 + p0) * 512 + g0;
#pragma unroll
    for (int i = 0; i < 16; ++i) {
        int pr = r0 + 4 * i;
        dst[(size_t)pr * 512 + c] = tile[c][pr];
    }
}

// ---------------- K1b: reduce partials -> norms; zero HSUM ----------------
__global__ __launch_bounds__(256) void k_norm(float* __restrict__ ws) {
    int bid = blockIdx.x;
    if (bid == 16) {
        int t = threadIdx.x;
        ws[OFF_HSUMG + t] = 0.f;
        ws[OFF_HSUMP + t] = 0.f;
        return;
    }
    int idx = bid * 256 + threadIdx.x;   // 0..4095
    int side = idx >> 11, lr = idx & 2047;
    const float* part = ws + (side ? OFF_NPP : OFF_NPG) + lr;
    float s = 0.f;
#pragma unroll
    for (int j = 0; j < 8; ++j) s += part[j * 2048];
    ws[(side ? OFF_NORMP : OFF_NORMG) + lr] = s;
}

// ---------------- K2: S sums; block 1024 does norm-maxes + U precompute ----------------
__global__ __launch_bounds__(256) void k_s(const float* __restrict__ obs,
                                           float* __restrict__ ws,
                                           const float* __restrict__ Wee_g,
                                           const float* __restrict__ Wef_g,
                                           const float* __restrict__ Wee_p,
                                           const float* __restrict__ Wef_p) {
    int bid = blockIdx.x;
    if (bid == 1024) {
        __shared__ float redg[4], redp[4];
        int t = threadIdx.x, lane = t & 63, w = t >> 6;
        float mg = 0.f, mp = 0.f;
        for (int k = t; k < 2048; k += 256) {
            mg = fmaxf(mg, ws[OFF_NORMG + k]);
            mp = fmaxf(mp, ws[OFF_NORMP + k]);
        }
        mg = wave_max(mg);
        mp = wave_max(mp);
        if (lane == 0) { redg[w] = mg; redp[w] = mp; }
        __syncthreads();
        if (t == 0) {
            ws[OFF_MAXG] = fmaxf(fmaxf(redg[0], redg[1]), fmaxf(redg[2], redg[3]));
            ws[OFF_MAXP] = fmaxf(fmaxf(redp[0], redp[1]), fmaxf(redp[2], redp[3]));
        }
        if (t < 128) {
            int side = t >> 6, f = t & 63;
            const float* Wee = side ? Wee_p : Wee_g;
            const float* Wef = side ? Wef_p : Wef_g;
            float u = 0.f;
#pragma unroll
            for (int e = 0; e < 63; ++e) u += fmaxf(Wee[e], 0.f) * Wef[e * 64 + f];
            ws[OFF_U + t] = u;
        }
        return;
    }
    int t = threadIdx.x, w = t >> 6, lane = t & 63;
    int row = bid * 4 + w;          // 0..4095
    int side = row >> 11;           // 0 = g rows, 1 = p rows
    int lr = row & 2047;            // b*512 + r
    int b = lr >> 9;
    const float* arow = side ? (ws + OFF_OBST + (size_t)lr * 512)
                             : (obs + (size_t)lr * 512);
    const float* wnorm = ws + (side ? OFF_NORMG : OFF_NORMP) + b * 512;
    float s = 0.f;
#pragma unroll
    for (int k = 0; k < 8; ++k) {
        int p = lane + 64 * k;
        float v = arow[p];
        if (v != 0.f) s += wnorm[p];
    }
    s = wave_sum(s) * (1.f / 512.f);
    if (lane == 0) ws[(side ? OFF_SP : OFF_SG) + lr] = s;
}

// ---------------- K3: init h and e (edge embedding collapsed) ----------------
__global__ __launch_bounds__(256) void k_init(const float* __restrict__ Wi_g,
                                              const float* __restrict__ Wi_p,
                                              const float* __restrict__ Wef_g,
                                              const float* __restrict__ Wef_p,
                                              float* __restrict__ ws) {
    int idx = blockIdx.x * 256 + threadIdx.x;  // 0..262143
    int row = idx >> 6, f = idx & 63;
    int side = row >> 11, lr = row & 2047;
    float norm = ws[(side ? OFF_NORMP : OFF_NORMG) + lr];
    float nf1 = norm > 0.f ? norm : 1.f;
    float nf = norm * (1.f / 512.f);
    const float* Wi = side ? Wi_p : Wi_g;
    float h = fmaxf(nf * Wi[f], 0.f);
    ws[(side ? OFF_HA_P : OFF_HA_G) + (size_t)lr * 64 + f] = h;
    float A = ws[(side ? OFF_SP : OFF_SG) + lr] / nf1;
    float maxnf = fmaxf(ws[side ? OFF_MAXP : OFF_MAXG], 1.f);
    float C = norm / maxnf;
    float U = ws[OFF_U + side * 64 + f];
    const float* Wef = side ? Wef_p : Wef_g;
    float e = fmaxf(A * U + C * Wef[63 * 64 + f], 0.f);
    ws[(side ? OFF_EP : OFF_EG) + (size_t)lr * 64 + f] = e;
}

// ---------------- K4: one MPNN layer, both sides. 256 blocks x 1024 threads ----------------
// 16 waves/block (4/SIMD). Full opposite-side h staged in LDS (128 KB). K split
// 4-ways across wave-groups; each wave-group keeps the 4-row LDS amortization.
__global__ __launch_bounds__(1024, 4) void k_layer(const float* __restrict__ obs,
                                                   float* __restrict__ ws,
                                                   const float* __restrict__ Wmsg_g,
                                                   const float* __restrict__ Wupd_g,
                                                   const float* __restrict__ Wmsg_p,
                                                   const float* __restrict__ Wupd_p,
                                                   int layer, int hin_g, int hin_p,
                                                   int hout_g, int hout_p, int do_pool) {
    __shared__ float hbuf[512][NF];      // 128 KB
    __shared__ float aggp[4][16][NF];    // 16 KB (slab 0 reused for final agg; slab 1 for pool)
    __shared__ float m_lds[16][NF];      // 4 KB

    int side = blockIdx.x >> 7, tilei = blockIdx.x & 127;
    int row0 = tilei * 16;              // row index within side (= b*512 + r)
    int b = row0 >> 9;
    const float* adj   = side ? (ws + OFF_OBST + (size_t)row0 * 512)
                              : (obs + (size_t)row0 * 512);
    const float* h_opp = ws + (side ? hin_g : hin_p) + (size_t)b * 32768;
    const float* h_self= ws + (side ? hin_p : hin_g) + (size_t)row0 * 64;
    const float* e_b   = ws + (side ? OFF_EP : OFF_EG) + (size_t)row0 * 64;
    const float* nrm   = ws + (side ? OFF_NORMP : OFF_NORMG) + row0;
    const float* Wm    = (side ? Wmsg_p : Wmsg_g) + layer * 8192;
    const float* Wu    = (side ? Wupd_p : Wupd_g) + layer * 8192;
    float* h_out = ws + (side ? hout_p : hout_g) + (size_t)row0 * 64;
    float* hsum  = ws + (side ? OFF_HSUMP : OFF_HSUMG) + b * 64;

    int t = threadIdx.x, f = t & 63, w = t >> 6;    // w 0..15
    int kg = w >> 2, rh = w & 3;                    // k-group, row-slot

    // stage ALL of h_opp: 32768 floats = 8192 float4, 8 per thread
    {
        const float4* src = (const float4*)h_opp;
        float4* dst = (float4*)&hbuf[0][0];
#pragma unroll
        for (int i = 0; i < 8; ++i) dst[t + 1024 * i] = src[t + 1024 * i];
    }
    __syncthreads();

    // aggregation: rows rh, rh+4, rh+8, rh+12 over k in [kg*128, kg*128+128)
    float acc0 = 0.f, acc1 = 0.f, acc2 = 0.f, acc3 = 0.f;
    {
        const float4* a0 = (const float4*)(adj + (size_t)(rh + 0) * 512 + kg * 128);
        const float4* a1 = (const float4*)(adj + (size_t)(rh + 4) * 512 + kg * 128);
        const float4* a2 = (const float4*)(adj + (size_t)(rh + 8) * 512 + kg * 128);
        const float4* a3 = (const float4*)(adj + (size_t)(rh + 12) * 512 + kg * 128);
        const float* hcol = &hbuf[kg * 128][0] + f;
#pragma unroll 8
        for (int p4 = 0; p4 < 32; ++p4) {
            float4 o0 = a0[p4], o1 = a1[p4], o2 = a2[p4], o3 = a3[p4];
#pragma unroll
            for (int j = 0; j < 4; ++j) {
                float hv = hcol[(size_t)(p4 * 4 + j) * 64];
                acc0 += ((const float*)&o0)[j] * hv;
                acc1 += ((const float*)&o1)[j] * hv;
                acc2 += ((const float*)&o2)[j] * hv;
                acc3 += ((const float*)&o3)[j] * hv;
            }
        }
    }
    aggp[kg][rh + 0][f] = acc0;
    aggp[kg][rh + 4][f] = acc1;
    aggp[kg][rh + 8][f] = acc2;
    aggp[kg][rh + 12][f] = acc3;
    __syncthreads();

    // combine partials + normalize: one output per thread (r = w, col = f).
    // Each (r,f) address is read and rewritten only by its owning thread.
    {
        int r = w;
        float rcp = 1.f / fmaxf(nrm[r], 1.f);
        float agg = (aggp[0][r][f] + aggp[1][r][f] + aggp[2][r][f] + aggp[3][r][f]) * rcp;
        aggp[0][r][f] = agg;
    }
    __syncthreads();

    // phase 2: m[r][f] = relu([agg, e] @ Wm), one output per thread
    {
        int r = w;
        const float* aggr = &aggp[0][r][0];
        const float* er = e_b + (size_t)r * 64;
        float mv = 0.f;
#pragma unroll 8
        for (int k = 0; k < 64; ++k) mv += aggr[k] * Wm[k * 64 + f];
#pragma unroll 8
        for (int k = 0; k < 64; ++k) mv += er[k] * Wm[(64 + k) * 64 + f];
        m_lds[r][f] = fmaxf(mv, 0.f);
    }
    __syncthreads();

    // phase 3: h_new[r][f] = relu([h, m] @ Wu), one output per thread
    {
        int r = w;
        const float* hs = h_self + (size_t)r * 64;
        const float* mr = &m_lds[r][0];
        float hv = 0.f;
#pragma unroll 8
        for (int k = 0; k < 64; ++k) hv += hs[k] * Wu[k * 64 + f];
#pragma unroll 8
        for (int k = 0; k < 64; ++k) hv += mr[k] * Wu[(64 + k) * 64 + f];
        hv = fmaxf(hv, 0.f);
        h_out[(size_t)r * 64 + f] = hv;
        if (do_pool) {
            aggp[1][r][f] = hv;
            __syncthreads();
            if (t < 256) {
                int r4 = t >> 6;
                float s = aggp[1][r4][f] + aggp[1][r4 + 4][f]
                        + aggp[1][r4 + 8][f] + aggp[1][r4 + 12][f];
                atomicAdd(&hsum[f], s);
            }
        }
    }
}

// ---------------- K5: pooled readout constant c1[b] ----------------
__global__ __launch_bounds__(256) void k_pool(const float* __restrict__ Wpg,
                                              const float* __restrict__ Wpp,
                                              const float* __restrict__ Wro,
                                              const float* __restrict__ bro,
                                              float* __restrict__ ws) {
    int t = threadIdx.x;          // 256 = B*64
    int b = t >> 6, f = t & 63;
    const float* hsg = ws + OFF_HSUMG + b * 64;
    const float* hsp = ws + OFF_HSUMP + b * 64;
    float vg = 0.f, vp = 0.f;
#pragma unroll
    for (int k = 0; k < 64; ++k) {
        vg += (hsg[k] * (1.f / 512.f)) * Wpg[k * 64 + f];
        vp += (hsp[k] * (1.f / 512.f)) * Wpp[k * 64 + f];
    }
    float hp = fmaxf(vg + vp, 0.f);
    float c = wave_sum(hp * Wro[f]);
    if (f == 0) ws[OFF_C1 + b] = c + bro[0];
}

// ---------------- K6: out[b,g] = c1[b] + h_g[b,g,:] . Wro[64:128] ----------------
__global__ __launch_bounds__(256) void k_out(const float* __restrict__ Wro,
                                             const float* __restrict__ ws,
                                             float* __restrict__ out) {
    int idx = blockIdx.x * 256 + threadIdx.x;   // 0..2047
    int b = idx >> 9;
    const float4* hrow = (const float4*)(ws + OFF_HB_G + (size_t)idx * 64);
    float s = 0.f;
#pragma unroll
    for (int k4 = 0; k4 < 16; ++k4) {
        float4 h4 = hrow[k4];
        s += h4.x * Wro[64 + k4 * 4 + 0];
        s += h4.y * Wro[64 + k4 * 4 + 1];
        s += h4.z * Wro[64 + k4 * 4 + 2];
        s += h4.w * Wro[64 + k4 * 4 + 3];
    }
    out[idx] = ws[OFF_C1 + b] + s;
}

extern "C" void kernel_launch(void* const* d_in, const int* in_sizes, int n_in,
                              void* d_out, int out_size, void* d_ws, size_t ws_size,
                              hipStream_t stream) {
    const float* obs   = (const float*)d_in[0];
    const float* Wi_g  = (const float*)d_in[1];
    const float* Wi_p  = (const float*)d_in[2];
    const float* Wee_g = (const float*)d_in[3];
    const float* Wef_g = (const float*)d_in[4];
    const float* Wee_p = (const float*)d_in[5];
    const float* Wef_p = (const float*)d_in[6];
    const float* Wm_g  = (const float*)d_in[7];
    const float* Wu_g  = (const float*)d_in[8];
    const float* Wm_p  = (const float*)d_in[9];
    const float* Wu_p  = (const float*)d_in[10];
    const float* Wpg   = (const float*)d_in[11];
    const float* Wpp   = (const float*)d_in[12];
    const float* Wro   = (const float*)d_in[13];
    const float* bro   = (const float*)d_in[14];
    float* ws  = (float*)d_ws;
    float* out = (float*)d_out;

    k_prep<<<dim3(64, 4), 256, 0, stream>>>(obs, ws);
    k_norm<<<17, 256, 0, stream>>>(ws);
    k_s<<<1025, 256, 0, stream>>>(obs, ws, Wee_g, Wef_g, Wee_p, Wef_p);
    k_init<<<1024, 256, 0, stream>>>(Wi_g, Wi_p, Wef_g, Wef_p, ws);
    k_layer<<<256, 1024, 0, stream>>>(obs, ws, Wm_g, Wu_g, Wm_p, Wu_p,
                                      0, OFF_HA_G, OFF_HA_P, OFF_HB_G, OFF_HB_P, 0);
    k_layer<<<256, 1024, 0, stream>>>(obs, ws, Wm_g, Wu_g, Wm_p, Wu_p,
                                      1, OFF_HB_G, OFF_HB_P, OFF_HA_G, OFF_HA_P, 0);
    k_layer<<<256, 1024, 0, stream>>>(obs, ws, Wm_g, Wu_g, Wm_p, Wu_p,
                                      2, OFF_HA_G, OFF_HA_P, OFF_HB_G, OFF_HB_P, 1);
    k_pool<<<1, 256, 0, stream>>>(Wpg, Wpp, Wro, bro, ws);
    k_out<<<8, 256, 0, stream>>>(Wro, ws, out);
}

// Round 5
// 128.062 us; speedup vs baseline: 1.0379x; 1.0379x over previous
//
#include <hip/hip_runtime.h>

#define NF 64

// workspace float offsets
#define OFF_NORMG   0          // 2048
#define OFF_NORMP   2048       // 2048
#define OFF_SG      4096       // 2048
#define OFF_SP      6144       // 2048
#define OFF_MAXG    8192       // 1 (float)
#define OFF_MAXP    8193       // 1 (float)
#define OFF_U       8194       // 128
#define OFF_HSUMG   8322       // 256
#define OFF_HSUMP   8578       // 256
#define OFF_C1      8834       // 4
#define OFF_NPG     9216       // 8*2048 partial row counts (g side)
#define OFF_NPP     25600      // 8*2048 partial col counts (p side)
#define OFF_HA_G    41984      // 131072
#define OFF_HA_P    173056
#define OFF_HB_G    304128
#define OFF_HB_P    435200
#define OFF_EG      566272
#define OFF_EP      697344
#define OFF_OBST    828416     // 1048576 floats
#define OFF_PART    1900544    // 4 slices * 4096 rows * 64 = 1048576 floats (ws is 256 MB)

static __device__ __forceinline__ float wave_sum(float v) {
    for (int off = 32; off; off >>= 1) v += __shfl_down(v, off, 64);
    return v;
}
static __device__ __forceinline__ float wave_max(float v) {
    for (int off = 32; off; off >>= 1) v = fmaxf(v, __shfl_down(v, off, 64));
    return v;
}

// ---------------- K1: transpose obs -> obsT, partial row/col nonzero counts ----------------
__global__ __launch_bounds__(256) void k_prep(const float* __restrict__ obs,
                                              float* __restrict__ ws) {
    __shared__ float tile[64][65];
    __shared__ float cc[4][64];
    int b = blockIdx.y, t = threadIdx.x;
    int tg = blockIdx.x >> 3, tp = blockIdx.x & 7;
    int g0 = tg * 64, p0 = tp * 64;
    int c = t & 63, r0 = t >> 6;   // r0 = wave id (0..3)
    const float* src = obs + ((size_t)b * 512 + g0) * 512 + p0;
    float colcnt = 0.f;
#pragma unroll
    for (int i = 0; i < 16; ++i) {
        int r = r0 + 4 * i;
        float v = src[(size_t)r * 512 + c];
        tile[r][c] = v;
        float nz = (v != 0.f) ? 1.f : 0.f;
        colcnt += nz;
        nz = wave_sum(nz);
        if (c == 0) ws[OFF_NPG + tp * 2048 + b * 512 + g0 + r] = nz;
    }
    cc[r0][c] = colcnt;
    __syncthreads();
    if (r0 == 0)
        ws[OFF_NPP + tg * 2048 + b * 512 + p0 + c] =
            cc[0][c] + cc[1][c] + cc[2][c] + cc[3][c];
    float* dst = ws + OFF_OBST + ((size_t)b * 512 + p0) * 512 + g0;
#pragma unroll
    for (int i = 0; i < 16; ++i) {
        int pr = r0 + 4 * i;
        dst[(size_t)pr * 512 + c] = tile[c][pr];
    }
}

// ---------------- K1b: reduce partials -> norms ----------------
__global__ __launch_bounds__(256) void k_norm(float* __restrict__ ws) {
    int idx = blockIdx.x * 256 + threadIdx.x;   // 0..4095
    int side = idx >> 11, lr = idx & 2047;
    const float* part = ws + (side ? OFF_NPP : OFF_NPG) + lr;
    float s = 0.f;
#pragma unroll
    for (int j = 0; j < 8; ++j) s += part[j * 2048];
    ws[(side ? OFF_NORMP : OFF_NORMG) + lr] = s;
}

// ---------------- K2: S sums; block 1024 does norm-maxes + U precompute ----------------
__global__ __launch_bounds__(256) void k_s(const float* __restrict__ obs,
                                           float* __restrict__ ws,
                                           const float* __restrict__ Wee_g,
                                           const float* __restrict__ Wef_g,
                                           const float* __restrict__ Wee_p,
                                           const float* __restrict__ Wef_p) {
    int bid = blockIdx.x;
    if (bid == 1024) {
        __shared__ float redg[4], redp[4];
        int t = threadIdx.x, lane = t & 63, w = t >> 6;
        float mg = 0.f, mp = 0.f;
        for (int k = t; k < 2048; k += 256) {
            mg = fmaxf(mg, ws[OFF_NORMG + k]);
            mp = fmaxf(mp, ws[OFF_NORMP + k]);
        }
        mg = wave_max(mg);
        mp = wave_max(mp);
        if (lane == 0) { redg[w] = mg; redp[w] = mp; }
        __syncthreads();
        if (t == 0) {
            ws[OFF_MAXG] = fmaxf(fmaxf(redg[0], redg[1]), fmaxf(redg[2], redg[3]));
            ws[OFF_MAXP] = fmaxf(fmaxf(redp[0], redp[1]), fmaxf(redp[2], redp[3]));
        }
        if (t < 128) {
            int side = t >> 6, f = t & 63;
            const float* Wee = side ? Wee_p : Wee_g;
            const float* Wef = side ? Wef_p : Wef_g;
            float u = 0.f;
#pragma unroll
            for (int e = 0; e < 63; ++e) u += fmaxf(Wee[e], 0.f) * Wef[e * 64 + f];
            ws[OFF_U + t] = u;
        }
        return;
    }
    int t = threadIdx.x, w = t >> 6, lane = t & 63;
    int row = bid * 4 + w;          // 0..4095
    int side = row >> 11;           // 0 = g rows, 1 = p rows
    int lr = row & 2047;            // b*512 + r
    int b = lr >> 9;
    const float* arow = side ? (ws + OFF_OBST + (size_t)lr * 512)
                             : (obs + (size_t)lr * 512);
    const float* wnorm = ws + (side ? OFF_NORMG : OFF_NORMP) + b * 512;
    float s = 0.f;
#pragma unroll
    for (int k = 0; k < 8; ++k) {
        int p = lane + 64 * k;
        float v = arow[p];
        if (v != 0.f) s += wnorm[p];
    }
    s = wave_sum(s) * (1.f / 512.f);
    if (lane == 0) ws[(side ? OFF_SP : OFF_SG) + lr] = s;
}

// ---------------- K3: init h and e (edge embedding collapsed) ----------------
__global__ __launch_bounds__(256) void k_init(const float* __restrict__ Wi_g,
                                              const float* __restrict__ Wi_p,
                                              const float* __restrict__ Wef_g,
                                              const float* __restrict__ Wef_p,
                                              float* __restrict__ ws) {
    int idx = blockIdx.x * 256 + threadIdx.x;  // 0..262143
    int row = idx >> 6, f = idx & 63;
    int side = row >> 11, lr = row & 2047;
    float norm = ws[(side ? OFF_NORMP : OFF_NORMG) + lr];
    float nf1 = norm > 0.f ? norm : 1.f;
    float nf = norm * (1.f / 512.f);
    const float* Wi = side ? Wi_p : Wi_g;
    float h = fmaxf(nf * Wi[f], 0.f);
    ws[(side ? OFF_HA_P : OFF_HA_G) + (size_t)lr * 64 + f] = h;
    float A = ws[(side ? OFF_SP : OFF_SG) + lr] / nf1;
    float maxnf = fmaxf(ws[side ? OFF_MAXP : OFF_MAXG], 1.f);
    float C = norm / maxnf;
    float U = ws[OFF_U + side * 64 + f];
    const float* Wef = side ? Wef_p : Wef_g;
    float e = fmaxf(A * U + C * Wef[63 * 64 + f], 0.f);
    ws[(side ? OFF_EP : OFF_EG) + (size_t)lr * 64 + f] = e;
}

// ---------------- K4a: aggregation, split-K. 1024 blocks x 256 threads, 4/CU ----------------
// block = (slice 0..3, side 0..1, tile 0..127): 16 rows x 128-k slice.
// adj tile AND h slice staged in LDS via coalesced per-lane loads (high MLP);
// inner loop is pure LDS: adj b128 broadcast + h b32 (2-way, free).
__global__ __launch_bounds__(256) void k_agg(const float* __restrict__ obs,
                                             float* __restrict__ ws,
                                             int hin_g, int hin_p) {
    __shared__ float h_lds[128][NF];    // 32 KB
    __shared__ float a_lds[16][128];    // 8 KB
    int bid = blockIdx.x;
    int slice = bid >> 8, side = (bid >> 7) & 1, tile = bid & 127;
    int row0 = tile * 16, b = row0 >> 9, k0 = slice * 128;
    const float* adj = (side ? ws + OFF_OBST : obs) + (size_t)row0 * 512 + k0;
    const float* h_opp = ws + (side ? hin_g : hin_p) + ((size_t)b * 512 + k0) * 64;
    int t = threadIdx.x, f = t & 63, w = t >> 6;

    {   // stage h slice (128 x 64), 8 float4/thread, coalesced
        const float4* src = (const float4*)h_opp;
        float4* dst = (float4*)&h_lds[0][0];
#pragma unroll
        for (int i = 0; i < 8; ++i) dst[t + 256 * i] = src[t + 256 * i];
    }
    {   // stage adj tile (16 x 128), 2 float4/thread, coalesced within rows
        float4* dst = (float4*)&a_lds[0][0];
#pragma unroll
        for (int i = 0; i < 2; ++i) {
            int idx = t + 256 * i;
            int r = idx >> 5, c4 = idx & 31;
            dst[idx] = *(const float4*)(adj + (size_t)r * 512 + c4 * 4);
        }
    }
    __syncthreads();

    float acc0 = 0.f, acc1 = 0.f, acc2 = 0.f, acc3 = 0.f;
    const float* hc = &h_lds[0][0] + f;
#pragma unroll 4
    for (int k4 = 0; k4 < 32; ++k4) {
        float4 a0 = *(const float4*)&a_lds[w + 0][k4 * 4];
        float4 a1 = *(const float4*)&a_lds[w + 4][k4 * 4];
        float4 a2 = *(const float4*)&a_lds[w + 8][k4 * 4];
        float4 a3 = *(const float4*)&a_lds[w + 12][k4 * 4];
#pragma unroll
        for (int j = 0; j < 4; ++j) {
            float hv = hc[(size_t)(k4 * 4 + j) * 64];
            acc0 += ((const float*)&a0)[j] * hv;
            acc1 += ((const float*)&a1)[j] * hv;
            acc2 += ((const float*)&a2)[j] * hv;
            acc3 += ((const float*)&a3)[j] * hv;
        }
    }
    float* pp = ws + OFF_PART + ((size_t)slice * 4096 + side * 2048 + row0) * 64 + f;
    pp[(size_t)(w + 0) * 64] = acc0;
    pp[(size_t)(w + 4) * 64] = acc1;
    pp[(size_t)(w + 8) * 64] = acc2;
    pp[(size_t)(w + 12) * 64] = acc3;
}

// ---------------- K4b: MLP (msg + upd). 512 blocks x 256 threads, 2/CU ----------------
// block = (side, tile of 8 rows). Weights + rows staged in LDS; no uniform global loads.
__global__ __launch_bounds__(256) void k_mlp(float* __restrict__ ws,
                                             const float* __restrict__ Wmsg_g,
                                             const float* __restrict__ Wupd_g,
                                             const float* __restrict__ Wmsg_p,
                                             const float* __restrict__ Wupd_p,
                                             int layer, int hin_g, int hin_p,
                                             int hout_g, int hout_p) {
    __shared__ float Wml[128][NF];      // 32 KB
    __shared__ float Wul[128][NF];      // 32 KB
    __shared__ float row_l[4][8][NF];   // agg, e, h_self, m : 8 KB
    int bid = blockIdx.x, side = bid >> 8, tile = bid & 255;
    int row0 = tile * 8;                // lr = b*512 + r
    const float* Wm = (side ? Wmsg_p : Wmsg_g) + layer * 8192;
    const float* Wu = (side ? Wupd_p : Wupd_g) + layer * 8192;
    int t = threadIdx.x, f = t & 63, w = t >> 6;   // rows w and w+4

    {   // stage both weight matrices (2 x 32 KB), coalesced
        const float4* s1 = (const float4*)Wm;
        const float4* s2 = (const float4*)Wu;
        float4* d1 = (float4*)&Wml[0][0];
        float4* d2 = (float4*)&Wul[0][0];
#pragma unroll
        for (int i = 0; i < 8; ++i) {
            d1[t + 256 * i] = s1[t + 256 * i];
            d2[t + 256 * i] = s2[t + 256 * i];
        }
    }
    {   // stage rows: agg (combine 4 split-K partials, /nf1), e, h_self
        const float* nrm = ws + (side ? OFF_NORMP : OFF_NORMG) + row0;
        const float* e_b = ws + (side ? OFF_EP : OFF_EG) + (size_t)row0 * 64;
        const float* h_self = ws + (side ? hin_p : hin_g) + (size_t)row0 * 64;
#pragma unroll
        for (int rr = w; rr < 8; rr += 4) {
            const float* pp = ws + OFF_PART + ((size_t)side * 2048 + row0 + rr) * 64 + f;
            float s = pp[0] + pp[262144] + pp[524288] + pp[786432];
            row_l[0][rr][f] = s * (1.f / fmaxf(nrm[rr], 1.f));
            row_l[1][rr][f] = e_b[(size_t)rr * 64 + f];
            row_l[2][rr][f] = h_self[(size_t)rr * 64 + f];
        }
    }
    __syncthreads();

    // phase 2: m = relu([agg, e] @ Wm)
    float m0 = 0.f, m1 = 0.f;
#pragma unroll 4
    for (int k = 0; k < 64; ++k) {
        float wv = Wml[k][f];
        m0 += row_l[0][w][k] * wv;
        m1 += row_l[0][w + 4][k] * wv;
    }
#pragma unroll 4
    for (int k = 0; k < 64; ++k) {
        float wv = Wml[64 + k][f];
        m0 += row_l[1][w][k] * wv;
        m1 += row_l[1][w + 4][k] * wv;
    }
    row_l[3][w][f] = fmaxf(m0, 0.f);
    row_l[3][w + 4][f] = fmaxf(m1, 0.f);
    __syncthreads();

    // phase 3: h_new = relu([h, m] @ Wu)
    float h0 = 0.f, h1 = 0.f;
#pragma unroll 4
    for (int k = 0; k < 64; ++k) {
        float wv = Wul[k][f];
        h0 += row_l[2][w][k] * wv;
        h1 += row_l[2][w + 4][k] * wv;
    }
#pragma unroll 4
    for (int k = 0; k < 64; ++k) {
        float wv = Wul[64 + k][f];
        h0 += row_l[3][w][k] * wv;
        h1 += row_l[3][w + 4][k] * wv;
    }
    float* h_out = ws + (side ? hout_p : hout_g) + (size_t)row0 * 64;
    h_out[(size_t)w * 64 + f] = fmaxf(h0, 0.f);
    h_out[(size_t)(w + 4) * 64 + f] = fmaxf(h1, 0.f);
}

// ---------------- K4c: column sums of final h (replaces pooling atomics) ----------------
__global__ __launch_bounds__(256) void k_hsum(float* __restrict__ ws) {
    __shared__ float red[4][NF];
    int bid = blockIdx.x, side = bid >> 2, b = bid & 3;
    int t = threadIdx.x, f = t & 63, w = t >> 6;
    const float* h = ws + (side ? OFF_HB_P : OFF_HB_G) + (size_t)b * 32768;
    float s = 0.f;
    for (int r = w; r < 512; r += 4) s += h[(size_t)r * 64 + f];
    red[w][f] = s;
    __syncthreads();
    if (w == 0)
        ws[(side ? OFF_HSUMP : OFF_HSUMG) + b * 64 + f] =
            red[0][f] + red[1][f] + red[2][f] + red[3][f];
}

// ---------------- K5: pooled readout constant c1[b] ----------------
__global__ __launch_bounds__(256) void k_pool(const float* __restrict__ Wpg,
                                              const float* __restrict__ Wpp,
                                              const float* __restrict__ Wro,
                                              const float* __restrict__ bro,
                                              float* __restrict__ ws) {
    int t = threadIdx.x;          // 256 = B*64
    int b = t >> 6, f = t & 63;
    const float* hsg = ws + OFF_HSUMG + b * 64;
    const float* hsp = ws + OFF_HSUMP + b * 64;
    float vg = 0.f, vp = 0.f;
#pragma unroll
    for (int k = 0; k < 64; ++k) {
        vg += (hsg[k] * (1.f / 512.f)) * Wpg[k * 64 + f];
        vp += (hsp[k] * (1.f / 512.f)) * Wpp[k * 64 + f];
    }
    float hp = fmaxf(vg + vp, 0.f);
    float c = wave_sum(hp * Wro[f]);
    if (f == 0) ws[OFF_C1 + b] = c + bro[0];
}

// ---------------- K6: out[b,g] = c1[b] + h_g[b,g,:] . Wro[64:128] ----------------
__global__ __launch_bounds__(256) void k_out(const float* __restrict__ Wro,
                                             const float* __restrict__ ws,
                                             float* __restrict__ out) {
    int idx = blockIdx.x * 256 + threadIdx.x;   // 0..2047
    int b = idx >> 9;
    const float4* hrow = (const float4*)(ws + OFF_HB_G + (size_t)idx * 64);
    float s = 0.f;
#pragma unroll
    for (int k4 = 0; k4 < 16; ++k4) {
        float4 h4 = hrow[k4];
        s += h4.x * Wro[64 + k4 * 4 + 0];
        s += h4.y * Wro[64 + k4 * 4 + 1];
        s += h4.z * Wro[64 + k4 * 4 + 2];
        s += h4.w * Wro[64 + k4 * 4 + 3];
    }
    out[idx] = ws[OFF_C1 + b] + s;
}

extern "C" void kernel_launch(void* const* d_in, const int* in_sizes, int n_in,
                              void* d_out, int out_size, void* d_ws, size_t ws_size,
                              hipStream_t stream) {
    const float* obs   = (const float*)d_in[0];
    const float* Wi_g  = (const float*)d_in[1];
    const float* Wi_p  = (const float*)d_in[2];
    const float* Wee_g = (const float*)d_in[3];
    const float* Wef_g = (const float*)d_in[4];
    const float* Wee_p = (const float*)d_in[5];
    const float* Wef_p = (const float*)d_in[6];
    const float* Wm_g  = (const float*)d_in[7];
    const float* Wu_g  = (const float*)d_in[8];
    const float* Wm_p  = (const float*)d_in[9];
    const float* Wu_p  = (const float*)d_in[10];
    const float* Wpg   = (const float*)d_in[11];
    const float* Wpp   = (const float*)d_in[12];
    const float* Wro   = (const float*)d_in[13];
    const float* bro   = (const float*)d_in[14];
    float* ws  = (float*)d_ws;
    float* out = (float*)d_out;

    k_prep<<<dim3(64, 4), 256, 0, stream>>>(obs, ws);
    k_norm<<<16, 256, 0, stream>>>(ws);
    k_s<<<1025, 256, 0, stream>>>(obs, ws, Wee_g, Wef_g, Wee_p, Wef_p);
    k_init<<<1024, 256, 0, stream>>>(Wi_g, Wi_p, Wef_g, Wef_p, ws);

    // layer 0: HA -> HB
    k_agg<<<1024, 256, 0, stream>>>(obs, ws, OFF_HA_G, OFF_HA_P);
    k_mlp<<<512, 256, 0, stream>>>(ws, Wm_g, Wu_g, Wm_p, Wu_p, 0,
                                   OFF_HA_G, OFF_HA_P, OFF_HB_G, OFF_HB_P);
    // layer 1: HB -> HA
    k_agg<<<1024, 256, 0, stream>>>(obs, ws, OFF_HB_G, OFF_HB_P);
    k_mlp<<<512, 256, 0, stream>>>(ws, Wm_g, Wu_g, Wm_p, Wu_p, 1,
                                   OFF_HB_G, OFF_HB_P, OFF_HA_G, OFF_HA_P);
    // layer 2: HA -> HB
    k_agg<<<1024, 256, 0, stream>>>(obs, ws, OFF_HA_G, OFF_HA_P);
    k_mlp<<<512, 256, 0, stream>>>(ws, Wm_g, Wu_g, Wm_p, Wu_p, 2,
                                   OFF_HA_G, OFF_HA_P, OFF_HB_G, OFF_HB_P);

    k_hsum<<<8, 256, 0, stream>>>(ws);
    k_pool<<<1, 256, 0, stream>>>(Wpg, Wpp, Wro, bro, ws);
    k_out<<<8, 256, 0, stream>>>(Wro, ws, out);
}